// Round 8
// baseline (345.889 us; speedup 1.0000x reference)
//
#include <hip/hip_runtime.h>

#define S_LEN 2048
#define NHEAD 16

typedef float f32x4 __attribute__((ext_vector_type(4)));
typedef __bf16 bf16x8 __attribute__((ext_vector_type(8)));
typedef __bf16 bf16x4 __attribute__((ext_vector_type(4)));
typedef short s16x4 __attribute__((ext_vector_type(4)));

#define AS1 __attribute__((address_space(1)))
#define AS3 __attribute__((address_space(3)))

// async 16B/lane global->LDS; lds base wave-uniform (dest = base + lane*16)
__device__ __forceinline__ void gl2lds16(const void* g, void* l) {
    __builtin_amdgcn_global_load_lds((const AS1 unsigned int*)g,
                                     (AS3 unsigned int*)l, 16, 0, 0);
}
// barrier leaving newest N vmem loads in flight (proj kernel only)
__device__ __forceinline__ void wb_leave4() {
    asm volatile("s_waitcnt vmcnt(4)\n\ts_barrier" ::: "memory");
}
__device__ __forceinline__ void wb_drain() {
    asm volatile("s_waitcnt vmcnt(0)\n\ts_barrier" ::: "memory");
}

// ---------------- cast+swizzle A: q,k,v fp32[8192][1024] -> bf16, 16B chunks
// within each 64-elem k-segment permuted by (chunk ^ row&7) -------------------
__global__ __launch_bounds__(256) void cast_swizzle_kernel(
    const float* __restrict__ q, const float* __restrict__ k,
    const float* __restrict__ v, __bf16* __restrict__ out)
{
    int gid = blockIdx.x * 256 + threadIdx.x;
    int z   = gid >> 20;
    int rem = gid & 1048575;
    int r   = rem >> 7;
    int c   = rem & 127;
    const float* src = (z == 0 ? q : z == 1 ? k : v) + (size_t)r * 1024 + c * 8;
    float4 a = *(const float4*)src;
    float4 b = *(const float4*)(src + 4);
    bf16x8 t;
    t[0] = (__bf16)a.x; t[1] = (__bf16)a.y; t[2] = (__bf16)a.z; t[3] = (__bf16)a.w;
    t[4] = (__bf16)b.x; t[5] = (__bf16)b.y; t[6] = (__bf16)b.z; t[7] = (__bf16)b.w;
    int cp = (c & ~7) | ((c ^ r) & 7);
    *(bf16x8*)(out + (size_t)z * 8388608 + (size_t)r * 1024 + cp * 8) = t;
}

// ---------------- W transpose+cast+swizzle: W[k][n] f32 -> Wt[n][k] bf16 -----
__global__ __launch_bounds__(256) void transpose_cast_kernel(
    const float* __restrict__ W0, const float* __restrict__ W1,
    const float* __restrict__ W2, __bf16* __restrict__ Wt)
{
    int z = blockIdx.z;
    const float* W = (z == 0 ? W0 : z == 1 ? W1 : W2);
    __bf16* out = Wt + (size_t)z * 1048576;
    __shared__ float tile[32][33];
    int bx = blockIdx.x, by = blockIdx.y;
    int tid = threadIdx.x;
    int tx = tid & 31, ty = tid >> 5;
    for (int i = 0; i < 32; i += 8)
        tile[ty + i][tx] = W[(size_t)(by * 32 + ty + i) * 1024 + bx * 32 + tx];
    __syncthreads();
    if (tid < 128) {
        int nl = tid >> 2, kc = tid & 3;
        int n = bx * 32 + nl;
        int kbase = by * 32 + kc * 8;
        bf16x8 t;
        for (int j = 0; j < 8; j++) t[j] = (__bf16)tile[kc * 8 + j][nl];
        int cp = ((kbase >> 3) ^ n) & 7;
        *(bf16x8*)(out + (size_t)n * 1024 + (kbase & ~63) + cp * 8) = t;
    }
}

// ---------------- fused projection GEMM (z = 0:Q, 1:K, 2:V) ------------------
// BK=32, 3-slot LDS pipeline, 2-ahead prefetch, vmcnt-leave barriers.
// z==0 output pre-scaled by 0.125 (exact pow2; folds QK^T scale into Q).
__global__ __launch_bounds__(256, 3) void proj_gemm_kernel(
    const __bf16* __restrict__ Abf, const __bf16* __restrict__ Wt,
    __bf16* __restrict__ qw, __bf16* __restrict__ kw, __bf16* __restrict__ vt)
{
    int z = blockIdx.z;
    const __bf16* A = Abf + (size_t)z * 8388608;
    const __bf16* B = Wt + (size_t)z * 1048576;
    __shared__ __align__(16) char smem[49152];

    int tid = threadIdx.x;
    int bm = blockIdx.x, bn = blockIdx.y;
    int wave = tid >> 6, lane = tid & 63;
    int wm = (wave >> 1) * 64, wn = (wave & 1) * 64;
    int lrow = lane & 15;
    int q4 = lane >> 4;
    int l4r = lane >> 2, j4 = lane & 3;

    auto pf = [&](int kb) {
        int sl = kb % 3;
        int k0 = kb * 32;
        int segbyte = (k0 >> 6) * 128;
        int cbase = (k0 & 32) >> 3;
        for (int i = 0; i < 2; i++) {
            int r = wave * 32 + i * 16 + l4r;
            int cl = j4 ^ ((r >> 1) & 3);
            int phys = ((cbase + cl) ^ r) & 7;
            gl2lds16((const char*)A + (size_t)(bm * 128 + r) * 2048 + segbyte + phys * 16,
                     smem + sl * 8192 + wave * 2048 + i * 1024);
            gl2lds16((const char*)B + (size_t)(bn * 128 + r) * 2048 + segbyte + phys * 16,
                     smem + 24576 + sl * 8192 + wave * 2048 + i * 1024);
        }
    };

    f32x4 zero = {0.f, 0.f, 0.f, 0.f};
    f32x4 acc[4][4];
    for (int mt = 0; mt < 4; mt++)
        for (int nt = 0; nt < 4; nt++) acc[mt][nt] = zero;

    pf(0); pf(1);
    __syncthreads();
    for (int kb = 0; kb < 32; kb++) {
        if (kb == 31) wb_drain(); else wb_leave4();
        if (kb + 2 < 32) pf(kb + 2);
        int sA = (kb % 3) * 8192, sB = 24576 + (kb % 3) * 8192;
        bf16x8 af[4], bfv[4];
        for (int mt = 0; mt < 4; mt++) {
            int r = wm + mt * 16 + lrow;
            af[mt] = *(const bf16x8*)(smem + sA + r * 64 + (q4 ^ ((r >> 1) & 3)) * 16);
        }
        for (int nt = 0; nt < 4; nt++) {
            int r = wn + nt * 16 + lrow;
            bfv[nt] = *(const bf16x8*)(smem + sB + r * 64 + (q4 ^ ((r >> 1) & 3)) * 16);
        }
        for (int mt = 0; mt < 4; mt++)
            for (int nt = 0; nt < 4; nt++)
                acc[mt][nt] = __builtin_amdgcn_mfma_f32_16x16x32_bf16(
                    af[mt], bfv[nt], acc[mt][nt], 0, 0, 0);
    }
    __syncthreads();
    __bf16* T = (__bf16*)smem;     // row stride 136 elems (272 B)

    float oscale = (z == 0) ? 0.125f : 1.0f;
    int rowoff = q4 * 4;
    int b = bm >> 4;
    int s_base = (bm & 15) * 128;
    if (z < 2) {
        for (int mt = 0; mt < 4; mt++) {
            for (int nt = 0; nt < 4; nt++) {
                int n_local = wn + nt * 16 + lrow;
                int hl = n_local >> 6, d = n_local & 63;
                for (int reg = 0; reg < 4; reg++) {
                    int s_local = wm + mt * 16 + rowoff + reg;
                    int s = s_base + s_local;
                    int dp = (d & 7) | ((((d >> 3) ^ s) & 7) << 3);
                    T[s_local * 136 + hl * 64 + dp] = (__bf16)(acc[mt][nt][reg] * oscale);
                }
            }
        }
        __syncthreads();
        char* gq = (char*)(z == 0 ? qw : kw);
        for (int i = 0; i < 8; i++) {
            int id = tid + i * 256;
            int hl = id >> 10, r = (id >> 3) & 127, j = id & 7;
            float4 val = *(float4*)((char*)T + r * 272 + hl * 128 + j * 16);
            *(float4*)(gq + ((size_t)((b * 16 + bn * 2 + hl) * 2048) + s_base + r) * 128
                          + j * 16) = val;
        }
    } else {
        for (int mt = 0; mt < 4; mt++) {
            int s0 = wm + mt * 16 + rowoff;
            int seg = s0 >> 6, j0 = s0 & 63;
            for (int nt = 0; nt < 4; nt++) {
                int n_local = wn + nt * 16 + lrow;
                int d = n_local & 63;
                int hi = ((j0 >> 3) ^ d) & 7;
                bf16x4 pk;
                for (int reg = 0; reg < 4; reg++) pk[reg] = (__bf16)acc[mt][nt][reg];
                *(bf16x4*)&T[n_local * 136 + seg * 64 + hi * 8 + (j0 & 7)] = pk;
            }
        }
        __syncthreads();
        char* gv = (char*)vt;
        for (int i = 0; i < 8; i++) {
            int id = tid + i * 256;
            int nl = id >> 4, j = id & 15;
            int hl = nl >> 6, dv = nl & 63;
            float4 val = *(float4*)((char*)T + nl * 272 + j * 16);
            *(float4*)(gv + (((size_t)((b * 16 + bn * 2 + hl) * 64 + dv)) * 2048 + s_base) * 2
                          + j * 16) = val;
        }
    }
}

// ---------------- flash attention: wave-independent kv tiles, barrier-free
// main loop, NO LDS P round-trip. S^T C-layout (query=mloc, keys q4*4+reg)
// is exactly the B-operand layout of mfma_f32_16x16x16 (k = q4*4 + i), so
// PV runs as O^T += MFMA(A=V^T-frag, B=p-in-registers) straight from exp.
__global__ __launch_bounds__(256, 2) void attn_kernel(
    const __bf16* __restrict__ QW, const __bf16* __restrict__ KW,
    const __bf16* __restrict__ VT, const float* __restrict__ v_mask,
    const float* __restrict__ q_mask, float* __restrict__ out)
{
    int bx = blockIdx.x;
    int qb = (bx == 0) ? 0 : 32 - bx;   // deg-capable qb=0 first, then heavy
    int bh = blockIdx.y;
    int b = bh >> 4, h = bh & 15;

    __shared__ __align__(16) char lds[18704];
    char*  buf  = lds;                     // 4 waves x 4352B epilogue partials
    float* lbuf = (float*)(lds + 17408);   // [64 query][4 wave] l partials
    float* lsh  = (float*)(lds + 18432);   // [64] final l
    int*   flag = (int*)(lds + 18688);

    int tid = threadIdx.x;
    int wave = tid >> 6, lane = tid & 63;
    int mloc = lane & 15;
    int q4 = lane >> 4;
    int x7 = mloc & 7;

    const char* Qrow = (const char*)QW + ((size_t)bh * 2048 + qb * 64) * 128;
    const char* Krow = (const char*)KW + (size_t)bh * 2048 * 128;
    const char* Vrow = (const char*)VT + (size_t)bh * 64 * 4096;
    const float* vmrow = v_mask + (size_t)b * 2048;

    if (tid == 0) *flag = 0;

    // Q B-fragments (pre-scaled by 0.125 in projection)
    bf16x8 qfr[4][2];
    for (int ntq = 0; ntq < 4; ntq++)
        for (int kc = 0; kc < 2; kc++)
            qfr[ntq][kc] = *(const bf16x8*)(Qrow + (ntq * 16 + mloc) * 128 +
                                            (((kc * 4 + q4) ^ x7) << 4));

    f32x4 zero = {0.f, 0.f, 0.f, 0.f};
    f32x4 o_acc[4][4];          // [query group ntq][dv group ntv], O^T layout
    for (int i = 0; i < 4; i++)
        for (int j = 0; j < 4; j++) o_acc[i][j] = zero;
    float lt[4] = {0.f, 0.f, 0.f, 0.f};

    for (int kb = wave; kb <= qb; kb += 4) {
        // V A-frags for K=16 MFMA: lane m=dv=ntv*16+mloc, k=keys mt*16+q4*4..+3
        bf16x4 vfr[4][4];
        for (int ntv = 0; ntv < 4; ntv++)
            for (int mt = 0; mt < 4; mt++)
                vfr[ntv][mt] = *(const bf16x4*)(Vrow +
                    (size_t)(ntv * 16 + mloc) * 4096 + kb * 128 +
                    (((2 * mt + (q4 >> 1)) ^ x7) << 4) + (q4 & 1) * 8);

        for (int half = 0; half < 2; half++) {
            bf16x8 kfr[2][2];
            for (int m2 = 0; m2 < 2; m2++)
                for (int kc = 0; kc < 2; kc++)
                    kfr[m2][kc] = *(const bf16x8*)(Krow +
                        (size_t)(kb * 64 + (half * 2 + m2) * 16 + mloc) * 128 +
                        (((kc * 4 + q4) ^ x7) << 4));
            f32x4 sacc[2][4];
            for (int m2 = 0; m2 < 2; m2++)
                for (int ntq = 0; ntq < 4; ntq++) sacc[m2][ntq] = zero;
            for (int kc = 0; kc < 2; kc++)
                for (int m2 = 0; m2 < 2; m2++)
                    for (int ntq = 0; ntq < 4; ntq++)
                        sacc[m2][ntq] = __builtin_amdgcn_mfma_f32_16x16x32_bf16(
                            kfr[m2][kc], qfr[ntq][kc], sacc[m2][ntq], 0, 0, 0);

            for (int m2 = 0; m2 < 2; m2++) {
                int mt = half * 2 + m2;
                float4 vm4 = *(const float4*)(vmrow + kb * 64 + mt * 16 + q4 * 4);
                float pen[4];
                pen[0] = fmaf(1.0f - vm4.x, 1.0e9f, 12.0f);
                pen[1] = fmaf(1.0f - vm4.y, 1.0e9f, 12.0f);
                pen[2] = fmaf(1.0f - vm4.z, 1.0e9f, 12.0f);
                pen[3] = fmaf(1.0f - vm4.w, 1.0e9f, 12.0f);
                for (int ntq = 0; ntq < 4; ntq++) {
                    float p[4];
                    for (int reg = 0; reg < 4; reg++)
                        p[reg] = __expf(sacc[m2][ntq][reg] - pen[reg]);
                    if (kb == qb)   // causal zeroing on diagonal tile
                        for (int reg = 0; reg < 4; reg++)
                            if (mt * 16 + q4 * 4 + reg > ntq * 16 + mloc) p[reg] = 0.f;
                    lt[ntq] += (p[0] + p[1]) + (p[2] + p[3]);
                    bf16x4 pk;
                    for (int reg = 0; reg < 4; reg++) pk[reg] = (__bf16)p[reg];
                    s16x4 pks = *(s16x4*)&pk;
                    for (int ntv = 0; ntv < 4; ntv++) {
                        s16x4 vv = *(s16x4*)&vfr[ntv][mt];
                        o_acc[ntq][ntv] = __builtin_amdgcn_mfma_f32_16x16x16bf16_1k(
                            vv, pks, o_acc[ntq][ntv], 0, 0, 0);
                    }
                }
            }
        }
    }

    // l: sum this lane's key-partials across q4 groups -> full l per query
    for (int ntq = 0; ntq < 4; ntq++) {
        lt[ntq] += __shfl_xor(lt[ntq], 16);
        lt[ntq] += __shfl_xor(lt[ntq], 32);
    }
    if (q4 == 0)
        for (int ntq = 0; ntq < 4; ntq++)
            lbuf[(ntq * 16 + mloc) * 4 + wave] = lt[ntq];
    __syncthreads();
    float ltot[4];
    bool mydeg = false;
    for (int ntq = 0; ntq < 4; ntq++) {
        float4 lv = *(const float4*)&lbuf[(ntq * 16 + mloc) * 4];
        ltot[ntq] = (lv.x + lv.y) + (lv.z + lv.w);
        mydeg |= (ltot[ntq] == 0.0f);
    }
    if (mydeg && lane == 0) *flag = 1;
    __syncthreads();

    if (*flag) {
        // degenerate queries (entire causal window masked): reference softmaxes
        // uniformly over {window} U {unmasked future} (all logits exactly -1e9)
        float l2[4] = {0.f, 0.f, 0.f, 0.f};
        for (int kb = wave; kb < 32; kb += 4) {
            bf16x4 vfr[4][4];
            for (int ntv = 0; ntv < 4; ntv++)
                for (int mt = 0; mt < 4; mt++)
                    vfr[ntv][mt] = *(const bf16x4*)(Vrow +
                        (size_t)(ntv * 16 + mloc) * 4096 + kb * 128 +
                        (((2 * mt + (q4 >> 1)) ^ x7) << 4) + (q4 & 1) * 8);
            for (int mt = 0; mt < 4; mt++) {
                float4 vm4 = *(const float4*)(vmrow + kb * 64 + mt * 16 + q4 * 4);
                float vmj[4] = {vm4.x, vm4.y, vm4.z, vm4.w};
                for (int ntq = 0; ntq < 4; ntq++) {
                    bool degrow = (ltot[ntq] == 0.0f);
                    int qrow = qb * 64 + ntq * 16 + mloc;
                    bf16x4 pk;
                    float cnt = 0.f;
                    for (int j = 0; j < 4; j++) {
                        int key = kb * 64 + mt * 16 + q4 * 4 + j;
                        float ind = degrow ? ((key <= qrow) ? 1.0f : vmj[j]) : 0.0f;
                        pk[j] = (__bf16)ind;
                        cnt += ind;
                    }
                    l2[ntq] += cnt;
                    s16x4 pks = *(s16x4*)&pk;
                    for (int ntv = 0; ntv < 4; ntv++) {
                        s16x4 vv = *(s16x4*)&vfr[ntv][mt];
                        o_acc[ntq][ntv] = __builtin_amdgcn_mfma_f32_16x16x16bf16_1k(
                            vv, pks, o_acc[ntq][ntv], 0, 0, 0);
                    }
                }
            }
        }
        for (int ntq = 0; ntq < 4; ntq++) {
            l2[ntq] += __shfl_xor(l2[ntq], 16);
            l2[ntq] += __shfl_xor(l2[ntq], 32);
        }
        if (q4 == 0)
            for (int ntq = 0; ntq < 4; ntq++)
                lbuf[(ntq * 16 + mloc) * 4 + wave] = l2[ntq];
        __syncthreads();
        for (int ntq = 0; ntq < 4; ntq++) {
            if (ltot[ntq] == 0.0f) {
                float4 lv = *(const float4*)&lbuf[(ntq * 16 + mloc) * 4];
                ltot[ntq] = (lv.x + lv.y) + (lv.z + lv.w);
            }
        }
    }

    if (wave == 0 && q4 == 0)
        for (int ntq = 0; ntq < 4; ntq++)
            lsh[ntq * 16 + mloc] = ltot[ntq];

    // cross-wave O reduction, one 16-query group at a time (buf row pad 272B)
    for (int ntq = 0; ntq < 4; ntq++) {
        for (int ntv = 0; ntv < 4; ntv++)
            *(f32x4*)(buf + wave * 4352 + mloc * 272 + (ntv * 16 + q4 * 4) * 4) =
                o_acc[ntq][ntv];
        __syncthreads();
        int q = tid >> 4, dvc = (tid & 15) * 4;
        float4 s = {0.f, 0.f, 0.f, 0.f};
        for (int w = 0; w < 4; w++) {
            float4 a = *(const float4*)(buf + w * 4352 + q * 272 + dvc * 4);
            s.x += a.x; s.y += a.y; s.z += a.z; s.w += a.w;
        }
        int qg = qb * 64 + ntq * 16 + q;
        float scale = q_mask[(size_t)b * 2048 + qg] / lsh[ntq * 16 + q];
        s.x *= scale; s.y *= scale; s.z *= scale; s.w *= scale;
        *(float4*)(out + ((size_t)(b * 2048 + qg)) * 1024 + h * 64 + dvc) = s;
        __syncthreads();
    }
}

// ---------------- launch ------------------------------------------------------
extern "C" void kernel_launch(void* const* d_in, const int* in_sizes, int n_in,
                              void* d_out, int out_size, void* d_ws, size_t ws_size,
                              hipStream_t stream)
{
    const float* q      = (const float*)d_in[0];
    const float* k      = (const float*)d_in[1];
    const float* v      = (const float*)d_in[2];
    const float* v_mask = (const float*)d_in[3];
    const float* q_mask = (const float*)d_in[4];
    const float* Wq     = (const float*)d_in[5];
    const float* Wk     = (const float*)d_in[6];
    const float* Wv     = (const float*)d_in[7];
    float* out = (float*)d_out;

    __bf16* Abf = (__bf16*)d_ws;                 // 3 x 8192 x 1024
    __bf16* Wt  = Abf + (size_t)3 * 8388608;     // 3 x 1024 x 1024
    __bf16* qw  = Wt + (size_t)3 * 1048576;      // [B*H][S][64] (x0.125)
    __bf16* kw  = qw + (size_t)8388608;
    __bf16* vt  = kw + (size_t)8388608;          // [B*H][64][S]

    cast_swizzle_kernel<<<12288, 256, 0, stream>>>(q, k, v, Abf);
    transpose_cast_kernel<<<dim3(32, 32, 3), 256, 0, stream>>>(Wq, Wk, Wv, Wt);
    proj_gemm_kernel<<<dim3(64, 8, 3), 256, 0, stream>>>(Abf, Wt, qw, kw, vt);
    attn_kernel<<<dim3(32, 64), 256, 0, stream>>>(qw, kw, vt, v_mask, q_mask, out);
}